// Round 4
// baseline (8477.430 us; speedup 1.0000x reference)
//
#include <hip/hip_runtime.h>
#include <hip/hip_cooperative_groups.h>

namespace cg = cooperative_groups;

typedef unsigned short u16;
typedef __attribute__((ext_vector_type(8))) short short8;
typedef __attribute__((ext_vector_type(4))) float f32x4;

__device__ __forceinline__ u16 f2bf(float f) {
  union { float f; unsigned u; } v; v.f = f;
  unsigned r = (v.u + 0x7fffu + ((v.u >> 16) & 1u)) >> 16;
  return (u16)r;
}
__device__ __forceinline__ float sigm(float x) { return 1.f / (1.f + __expf(-x)); }
__device__ __forceinline__ float tanh_(float x) { return 1.f - 2.f / (__expf(2.f * x) + 1.f); }
__device__ __forceinline__ f32x4 mfma16(short8 a, short8 b, f32x4 c) {
  return __builtin_amdgcn_mfma_f32_16x16x32_bf16(a, b, c, 0, 0, 0);
}
// async global->LDS, 16B per lane; LDS dest must be wave-uniform base + lane*16
__device__ __forceinline__ void gload_lds16(const u16* g, u16* l) {
  __builtin_amdgcn_global_load_lds((const __attribute__((address_space(1))) void*)g,
                                   (__attribute__((address_space(3))) void*)l, 16, 0, 0);
}

// ---------------- sizes ----------------
// B=64 T=50 L=64 VOCAB=30000 EMB=300 NF=256 HID=1024 OUT=32
#define NTILES 120         // (3+4+5)*10 conv K-step tiles of [4][256][8] bf16

// ---------------- prep: pack conv weights + Wp to bf16 ----------------
__global__ void prep_kernel(const float* __restrict__ cw3, const float* __restrict__ cw4,
                            const float* __restrict__ cw5, const float* __restrict__ h2ow,
                            u16* __restrict__ Wc, u16* __restrict__ Wpb) {
  const int NT = 1015808;  // 983040 Wc + 32768 Wpb
  for (int i = blockIdx.x * blockDim.x + threadIdx.x; i < NT; i += gridDim.x * blockDim.x) {
    if (i < 983040) {
      // Wc[T][kg][n][ke] = w_bank[n][e][j], e = kc*32+kg*8+ke, zero for e>=300
      int T = i >> 13, q = i & 8191;
      int kg = q >> 11, n = (q >> 3) & 255, ke = q & 7;
      int bank, tb; const float* cw;
      if (T < 30) { bank = 0; tb = T; cw = cw3; }
      else if (T < 70) { bank = 1; tb = T - 30; cw = cw4; }
      else { bank = 2; tb = T - 70; cw = cw5; }
      int j = tb / 10, kc = tb - 10 * (tb / 10);
      int e = kc * 32 + kg * 8 + ke, fs = 3 + bank;
      float vv = (e < 300) ? cw[(n * 300 + e) * fs + j] : 0.f;
      Wc[i] = f2bf(vv);
    } else {
      int k = i - 983040; int c = k >> 10, kk = k & 1023;
      Wpb[k] = f2bf(h2ow[c * 1792 + 768 + kk]);
    }
  }
}

// ---------------- conv: fused embed-gather + 3-bank conv GEMM + relu-maxpool ----------------
// (unchanged from round 3: 560us, 718 TF, MfmaUtil 32%)
__global__ __launch_bounds__(512, 1) void conv_kernel(
    const int* __restrict__ dlg, const float* __restrict__ emb, const u16* __restrict__ Wc,
    const float* __restrict__ cb3, const float* __restrict__ cb4, const float* __restrict__ cb5,
    float* __restrict__ feats) {
  extern __shared__ char smem[];
  u16* Al = (u16*)smem;                 // [128][328]
  u16* Bl = (u16*)(smem + 83968);       // [2][4][256][8]
  const int tid = threadIdx.x;
  const int u0 = blockIdx.x * 2;

  gload_lds16(Wc + tid * 8, Bl + tid * 8);
  gload_lds16(Wc + 4096 + tid * 8, Bl + 4096 + tid * 8);

  union Pack { u16 h[8]; int4 v; };
  #pragma unroll
  for (int p = 0; p < 10; ++p) {
    int task = tid + p * 512;           // 128 rows * 40 chunks
    int r = task / 40, ch = task - r * 40;
    int u = u0 + (r >> 6), tt = r & 63;
    int tok = dlg[u * 64 + tt];
    Pack pk;
    if (ch < 37) {
      const float4* s = (const float4*)(emb + tok * 300 + ch * 8);
      float4 x = s[0], y = s[1];
      pk.h[0] = f2bf(x.x); pk.h[1] = f2bf(x.y); pk.h[2] = f2bf(x.z); pk.h[3] = f2bf(x.w);
      pk.h[4] = f2bf(y.x); pk.h[5] = f2bf(y.y); pk.h[6] = f2bf(y.z); pk.h[7] = f2bf(y.w);
    } else if (ch == 37) {
      const float* s = emb + tok * 300;
      #pragma unroll
      for (int q = 0; q < 8; ++q) { int e = 296 + q; pk.h[q] = (e < 300) ? f2bf(s[e]) : (u16)0; }
    } else {
      pk.v = make_int4(0, 0, 0, 0);
    }
    *(int4*)&Al[r * 328 + ch * 8] = pk.v;
  }
  __syncthreads();

  const int l = tid & 63, v = tid >> 6;
  const int wm = v >> 2, wn = v & 3;
  const int lr = l & 15, lg = l >> 4;
  int T = 0, bb = 0;

  for (int bank = 0; bank < 3; ++bank) {
    const int fs = 3 + bank, Lout = 62 - bank;
    f32x4 acc[4][4];
    #pragma unroll
    for (int mi = 0; mi < 4; ++mi)
      #pragma unroll
      for (int ni = 0; ni < 4; ++ni) acc[mi][ni] = (f32x4){0.f, 0.f, 0.f, 0.f};

    for (int j = 0; j < fs; ++j) {
      for (int kc = 0; kc < 10; ++kc) {
        if (T + 1 < NTILES) {
          const u16* src = Wc + (T + 1) * 8192;
          u16* dst = Bl + (bb ^ 1) * 8192;
          gload_lds16(src + tid * 8, dst + tid * 8);
          gload_lds16(src + 4096 + tid * 8, dst + 4096 + tid * 8);
        }
        const int abase = (wm * 64 + lr + j) * 328 + kc * 32 + lg * 8;
        short8 af[4]; short8 bf[4];
        #pragma unroll
        for (int mi = 0; mi < 4; ++mi) af[mi] = *(const short8*)&Al[abase + mi * 16 * 328];
        const int bbase = bb * 8192 + lg * 2048 + (wn * 64 + lr) * 8;
        #pragma unroll
        for (int ni = 0; ni < 4; ++ni) bf[ni] = *(const short8*)&Bl[bbase + ni * 128];
        #pragma unroll
        for (int mi = 0; mi < 4; ++mi)
          #pragma unroll
          for (int ni = 0; ni < 4; ++ni) acc[mi][ni] = mfma16(af[mi], bf[ni], acc[mi][ni]);
        __syncthreads();
        bb ^= 1; ++T;
      }
    }
    const float* cb = (bank == 0) ? cb3 : ((bank == 1) ? cb4 : cb5);
    #pragma unroll
    for (int ni = 0; ni < 4; ++ni) {
      int f = wn * 64 + ni * 16 + lr;
      float bias = cb[f];
      float mx = 0.f;
      #pragma unroll
      for (int mi = 0; mi < 4; ++mi)
        #pragma unroll
        for (int r = 0; r < 4; ++r) {
          int t = mi * 16 + lg * 4 + r;
          float val = acc[mi][ni][r] + bias;
          if (t < Lout) mx = fmaxf(mx, val);
        }
      mx = fmaxf(mx, __shfl_xor(mx, 16, 64));
      mx = fmaxf(mx, __shfl_xor(mx, 32, 64));
      if (lg == 0) feats[(u0 + wm) * 768 + bank * 256 + f] = mx;
    }
  }
}

// ---------------- head_ft: headb[t][b][c] = h2o_b[c] + feats[b*50+t] . h2o_w[c][0:768] ----------------
__global__ __launch_bounds__(256) void headft_kernel(const float* __restrict__ feats,
                                                     const float* __restrict__ h2ow,
                                                     const float* __restrict__ h2ob,
                                                     float* __restrict__ headb) {
  extern __shared__ float Wt[];  // [768][33]
  const int tid = threadIdx.x, t = blockIdx.x;
  for (int i = tid; i < 32 * 768; i += 256) {
    int c = i / 768, k = i - 768 * c;
    Wt[k * 33 + c] = h2ow[c * 1792 + k];
  }
  __syncthreads();
  const int c = tid & 31, b0r = tid >> 5;
  float acc[8];
  #pragma unroll
  for (int i = 0; i < 8; ++i) acc[i] = h2ob[c];
  for (int k4 = 0; k4 < 192; ++k4) {
    float w0 = Wt[(k4 * 4 + 0) * 33 + c], w1 = Wt[(k4 * 4 + 1) * 33 + c];
    float w2 = Wt[(k4 * 4 + 2) * 33 + c], w3 = Wt[(k4 * 4 + 3) * 33 + c];
    #pragma unroll
    for (int i = 0; i < 8; ++i) {
      int b = b0r + 8 * i;
      float4 fv = *(const float4*)&feats[(b * 50 + t) * 768 + k4 * 4];
      acc[i] += fv.x * w0 + fv.y * w1 + fv.z * w2 + fv.w * w3;
    }
  }
  #pragma unroll
  for (int i = 0; i < 8; ++i) headb[t * 2048 + (b0r + 8 * i) * 32 + c] = acc[i];
}

// ---------------- persistent cooperative LSTM ----------------
// grid 256 x 256 threads (4 waves). Block bk owns hidden units [4bk,4bk+4) of BOTH layers:
// 16 gate rows n=g*4+r -> global row g*1024+4bk+r. Weight slices live in LDS (XOR-swizzled,
// conflict-free ds_read_b128); c0/c1 state lives in LDS for all 50 steps; h0/h1 exchanged
// via double-buffered global with threadfence + grid.sync (2 syncs/step).
#define LDS_W0   0        // u16 [16][1024] whh0 slice (swizzled)
#define LDS_W1I  32768    // u16 [16][1024] wih1 slice (swizzled)
#define LDS_W1H  65536    // u16 [16][1024] whh1 slice (swizzled)
#define LDS_WI0  98304    // u16 [16][32]   wih0 slice
#define LDS_PRED 99328    // u16 [64][32]   pred(t-1) bf16
#define LDS_GST  103424   // f32 [64][16]   gate staging
#define LDS_C0   107520   // f32 [4][64]    c0 state
#define LDS_C1   108544   // f32 [4][64]    c1 state
#define LDS_B0   109568   // f32 [16]
#define LDS_B1   109632   // f32 [16]
#define LDS_TOT  109696

__device__ __forceinline__ short8 wread(const char* base, int lr, int kbyte) {
  return *(const short8*)(base + lr * 2048 + (kbyte ^ ((lr & 7) << 4)));
}

__global__ __launch_bounds__(256, 1) void lstm_pers(
    const float* __restrict__ whh0, const float* __restrict__ wih0,
    const float* __restrict__ whh1, const float* __restrict__ wih1,
    const float* __restrict__ b0, const float* __restrict__ b1,
    const u16* __restrict__ Wpb, const float* __restrict__ headb,
    u16* __restrict__ h0g, u16* __restrict__ h1g, float* __restrict__ dout) {
  extern __shared__ char smem[];
  u16* predl = (u16*)(smem + LDS_PRED);
  float* gst = (float*)(smem + LDS_GST);
  float* c0s = (float*)(smem + LDS_C0);
  float* c1s = (float*)(smem + LDS_C1);
  float* b0s = (float*)(smem + LDS_B0);
  float* b1s = (float*)(smem + LDS_B1);
  const int tid = threadIdx.x, bk = blockIdx.x;
  cg::grid_group grid = cg::this_grid();

  // ---- stage weight slices fp32 -> bf16 -> swizzled LDS (once) ----
  union Pack { u16 h[8]; int4 v; };
  for (int i = tid; i < 2048; i += 256) {           // 16 rows x 128 chunks of 8
    int n = i >> 7, ck = i & 127;
    int grow = (n >> 2) * 1024 + 4 * bk + (n & 3);
    int gof = grow * 1024 + ck * 8;
    int dst = n * 2048 + ((ck * 16) ^ ((n & 7) << 4));
    Pack p; float4 x, y; const float4* s;
    s = (const float4*)(whh0 + gof); x = s[0]; y = s[1];
    p.h[0]=f2bf(x.x); p.h[1]=f2bf(x.y); p.h[2]=f2bf(x.z); p.h[3]=f2bf(x.w);
    p.h[4]=f2bf(y.x); p.h[5]=f2bf(y.y); p.h[6]=f2bf(y.z); p.h[7]=f2bf(y.w);
    *(int4*)(smem + LDS_W0 + dst) = p.v;
    s = (const float4*)(wih1 + gof); x = s[0]; y = s[1];
    p.h[0]=f2bf(x.x); p.h[1]=f2bf(x.y); p.h[2]=f2bf(x.z); p.h[3]=f2bf(x.w);
    p.h[4]=f2bf(y.x); p.h[5]=f2bf(y.y); p.h[6]=f2bf(y.z); p.h[7]=f2bf(y.w);
    *(int4*)(smem + LDS_W1I + dst) = p.v;
    s = (const float4*)(whh1 + gof); x = s[0]; y = s[1];
    p.h[0]=f2bf(x.x); p.h[1]=f2bf(x.y); p.h[2]=f2bf(x.z); p.h[3]=f2bf(x.w);
    p.h[4]=f2bf(y.x); p.h[5]=f2bf(y.y); p.h[6]=f2bf(y.z); p.h[7]=f2bf(y.w);
    *(int4*)(smem + LDS_W1H + dst) = p.v;
  }
  if (tid < 64) {                                    // wih0 slice 16x32 (no swizzle)
    int n = tid >> 2, ck = tid & 3;
    int grow = (n >> 2) * 1024 + 4 * bk + (n & 3);
    const float4* s = (const float4*)(wih0 + grow * 32 + ck * 8);
    float4 x = s[0], y = s[1];
    Pack p;
    p.h[0]=f2bf(x.x); p.h[1]=f2bf(x.y); p.h[2]=f2bf(x.z); p.h[3]=f2bf(x.w);
    p.h[4]=f2bf(y.x); p.h[5]=f2bf(y.y); p.h[6]=f2bf(y.z); p.h[7]=f2bf(y.w);
    *(int4*)(smem + LDS_WI0 + n * 64 + ck * 16) = p.v;
  }
  if (tid < 16) {
    int grow = (tid >> 2) * 1024 + 4 * bk + (tid & 3);
    b0s[tid] = b0[grow]; b1s[tid] = b1[grow];
  }
  c0s[tid] = 0.f; c1s[tid] = 0.f;
  __syncthreads();

  const int l = tid & 63, wv = tid >> 6;
  const int lr = l & 15, lg = l >> 4;

  for (int t = 0; t < 50; ++t) {
    const int cur = t & 1, prv = cur ^ 1;
    const u16* h0p = h0g + prv * 65536;
    const u16* h1p = h1g + prv * 65536;
    // ---- phase A: pred(t-1) [redundant per block] + layer-0 gates/state ----
    if (t > 0) {
      f32x4 z0 = {0.f,0.f,0.f,0.f}, z1 = {0.f,0.f,0.f,0.f};
      const u16* Ar = h1p + (wv * 16 + lr) * 1024 + lg * 8;
      const u16* Bp0 = Wpb + lr * 1024 + lg * 8;
      const u16* Bp1 = Wpb + (16 + lr) * 1024 + lg * 8;
      #pragma unroll 4
      for (int k = 0; k < 1024; k += 32) {
        short8 a = *(const short8*)(Ar + k);
        z0 = mfma16(a, *(const short8*)(Bp0 + k), z0);
        z1 = mfma16(a, *(const short8*)(Bp1 + k), z1);
      }
      const float* hb = headb + (t - 1) * 2048;
      #pragma unroll
      for (int r = 0; r < 4; ++r) {
        int b = wv * 16 + lg * 4 + r;
        float p0 = sigm(z0[r] + hb[b * 32 + lr]);
        float p1 = sigm(z1[r] + hb[b * 32 + 16 + lr]);
        predl[b * 32 + lr] = f2bf(p0);
        predl[b * 32 + 16 + lr] = f2bf(p1);
        if (bk == 0) {
          dout[b * 1600 + (t - 1) * 32 + lr] = p0;
          dout[b * 1600 + (t - 1) * 32 + 16 + lr] = p1;
        }
      }
    }
    __syncthreads();
    f32x4 g0 = {b0s[lr], b0s[lr], b0s[lr], b0s[lr]};
    if (t > 0) {
      short8 ap = *(const short8*)&predl[(wv * 16 + lr) * 32 + lg * 8];
      short8 bi = *(const short8*)(smem + LDS_WI0 + lr * 64 + lg * 16);
      g0 = mfma16(ap, bi, g0);
      const u16* Ah = h0p + (wv * 16 + lr) * 1024 + lg * 8;
      #pragma unroll 4
      for (int k = 0; k < 1024; k += 32) {
        short8 a = *(const short8*)(Ah + k);
        g0 = mfma16(a, wread(smem + LDS_W0, lr, k * 2 + lg * 16), g0);
      }
    }
    #pragma unroll
    for (int r = 0; r < 4; ++r) gst[(wv * 16 + lg * 4 + r) * 16 + lr] = g0[r];
    __syncthreads();
    {
      int b = tid & 63, hu = tid >> 6;
      float gi = gst[b * 16 + hu],     gf = gst[b * 16 + 4 + hu];
      float gg = gst[b * 16 + 8 + hu], go = gst[b * 16 + 12 + hu];
      float cold = c0s[hu * 64 + b];
      float c2 = sigm(gf) * cold + sigm(gi) * tanh_(gg);
      float h2 = sigm(go) * tanh_(c2);
      c0s[hu * 64 + b] = c2;
      h0g[cur * 65536 + b * 1024 + 4 * bk + hu] = f2bf(h2);
    }
    __threadfence();
    grid.sync();

    // ---- phase B: layer-1 gates/state ----
    const u16* h0c = h0g + cur * 65536;
    f32x4 g1 = {b1s[lr], b1s[lr], b1s[lr], b1s[lr]};
    {
      const u16* Ah = h0c + (wv * 16 + lr) * 1024 + lg * 8;
      #pragma unroll 4
      for (int k = 0; k < 1024; k += 32) {
        short8 a = *(const short8*)(Ah + k);
        g1 = mfma16(a, wread(smem + LDS_W1I, lr, k * 2 + lg * 16), g1);
      }
    }
    if (t > 0) {
      const u16* Ah = h1p + (wv * 16 + lr) * 1024 + lg * 8;
      #pragma unroll 4
      for (int k = 0; k < 1024; k += 32) {
        short8 a = *(const short8*)(Ah + k);
        g1 = mfma16(a, wread(smem + LDS_W1H, lr, k * 2 + lg * 16), g1);
      }
    }
    #pragma unroll
    for (int r = 0; r < 4; ++r) gst[(wv * 16 + lg * 4 + r) * 16 + lr] = g1[r];
    __syncthreads();
    {
      int b = tid & 63, hu = tid >> 6;
      float gi = gst[b * 16 + hu],     gf = gst[b * 16 + 4 + hu];
      float gg = gst[b * 16 + 8 + hu], go = gst[b * 16 + 12 + hu];
      float cold = c1s[hu * 64 + b];
      float c2 = sigm(gf) * cold + sigm(gi) * tanh_(gg);
      float h2 = sigm(go) * tanh_(c2);
      c1s[hu * 64 + b] = c2;
      h1g[cur * 65536 + b * 1024 + 4 * bk + hu] = f2bf(h2);
    }
    __threadfence();
    grid.sync();
  }

  // ---- final pred (t=49) ----
  if (bk == 0) {
    f32x4 z0 = {0.f,0.f,0.f,0.f}, z1 = {0.f,0.f,0.f,0.f};
    const u16* Ar = h1g + 65536 + (wv * 16 + lr) * 1024 + lg * 8;   // t=49 -> cur=1
    const u16* Bp0 = Wpb + lr * 1024 + lg * 8;
    const u16* Bp1 = Wpb + (16 + lr) * 1024 + lg * 8;
    #pragma unroll 4
    for (int k = 0; k < 1024; k += 32) {
      short8 a = *(const short8*)(Ar + k);
      z0 = mfma16(a, *(const short8*)(Bp0 + k), z0);
      z1 = mfma16(a, *(const short8*)(Bp1 + k), z1);
    }
    const float* hb = headb + 49 * 2048;
    #pragma unroll
    for (int r = 0; r < 4; ++r) {
      int b = wv * 16 + lg * 4 + r;
      dout[b * 1600 + 49 * 32 + lr] = sigm(z0[r] + hb[b * 32 + lr]);
      dout[b * 1600 + 49 * 32 + 16 + lr] = sigm(z1[r] + hb[b * 32 + 16 + lr]);
    }
  }
}

extern "C" void kernel_launch(void* const* d_in, const int* in_sizes, int n_in,
                              void* d_out, int out_size, void* d_ws, size_t ws_size,
                              hipStream_t stream) {
  const int* dlg = (const int*)d_in[0];
  const float* emb = (const float*)d_in[1];
  const float* cw3 = (const float*)d_in[2];
  const float* cb3 = (const float*)d_in[3];
  const float* cw4 = (const float*)d_in[4];
  const float* cb4 = (const float*)d_in[5];
  const float* cw5 = (const float*)d_in[6];
  const float* cb5 = (const float*)d_in[7];
  const float* wih0 = (const float*)d_in[8];
  const float* whh0 = (const float*)d_in[9];
  const float* b0 = (const float*)d_in[10];
  const float* wih1 = (const float*)d_in[11];
  const float* whh1 = (const float*)d_in[12];
  const float* b1 = (const float*)d_in[13];
  const float* h2ow = (const float*)d_in[14];
  const float* h2ob = (const float*)d_in[15];
  float* dout = (float*)d_out;
  char* ws = (char*)d_ws;

  u16* Wc    = (u16*)(ws + 0);          // 1966080 B
  u16* Wpb   = (u16*)(ws + 1966080);    // 65536 B
  float* feats = (float*)(ws + 2031616);   // 9830400 B
  float* headb = (float*)(ws + 11862016);  // 409600 B
  u16* h0g   = (u16*)(ws + 12271616);   // [2][64*1024] bf16 = 262144 B
  u16* h1g   = (u16*)(ws + 12533760);   // [2][64*1024] bf16 = 262144 B

  hipFuncSetAttribute((const void*)conv_kernel, hipFuncAttributeMaxDynamicSharedMemorySize, 116736);
  hipFuncSetAttribute((const void*)headft_kernel, hipFuncAttributeMaxDynamicSharedMemorySize, 101376);
  hipFuncSetAttribute((const void*)lstm_pers, hipFuncAttributeMaxDynamicSharedMemorySize, LDS_TOT);

  prep_kernel<<<dim3(1024), dim3(256), 0, stream>>>(cw3, cw4, cw5, h2ow, Wc, Wpb);
  conv_kernel<<<dim3(1600), dim3(512), 116736, stream>>>(dlg, emb, Wc, cb3, cb4, cb5, feats);
  headft_kernel<<<dim3(50), dim3(256), 101376, stream>>>(feats, h2ow, h2ob, headb);

  void* kargs[] = {(void*)&whh0, (void*)&wih0, (void*)&whh1, (void*)&wih1,
                   (void*)&b0, (void*)&b1, (void*)&Wpb, (void*)&headb,
                   (void*)&h0g, (void*)&h1g, (void*)&dout};
  hipLaunchCooperativeKernel((void*)lstm_pers, dim3(256), dim3(256), kargs, LDS_TOT, stream);
}

// Round 5
// 2695.916 us; speedup vs baseline: 3.1445x; 3.1445x over previous
//
#include <hip/hip_runtime.h>

typedef unsigned short u16;
typedef unsigned long long u64;
typedef __attribute__((ext_vector_type(8))) short short8;
typedef __attribute__((ext_vector_type(4))) float f32x4;

__device__ __forceinline__ u16 f2bf(float f) {
  union { float f; unsigned u; } v; v.f = f;
  unsigned r = (v.u + 0x7fffu + ((v.u >> 16) & 1u)) >> 16;
  return (u16)r;
}
__device__ __forceinline__ float sigm(float x) { return 1.f / (1.f + __expf(-x)); }
__device__ __forceinline__ float tanh_(float x) { return 1.f - 2.f / (__expf(2.f * x) + 1.f); }
__device__ __forceinline__ f32x4 mfma16(short8 a, short8 b, f32x4 c) {
  return __builtin_amdgcn_mfma_f32_16x16x32_bf16(a, b, c, 0, 0, 0);
}
// async global->LDS, 16B per lane; LDS dest must be wave-uniform base + lane*16
__device__ __forceinline__ void gload_lds16(const u16* g, u16* l) {
  __builtin_amdgcn_global_load_lds((const __attribute__((address_space(1))) void*)g,
                                   (__attribute__((address_space(3))) void*)l, 16, 0, 0);
}
// cache-bypassing h exchange: agent-scope relaxed atomics are served at the IF (LLC),
// the device coherence point -> no buffer_wbl2/buffer_inv fences needed anywhere.
__device__ __forceinline__ short8 hload(const u16* p) {
  union { u64 q[2]; short8 s; } u;
  u.q[0] = __hip_atomic_load((const u64*)p, __ATOMIC_RELAXED, __HIP_MEMORY_SCOPE_AGENT);
  u.q[1] = __hip_atomic_load((const u64*)(p + 4), __ATOMIC_RELAXED, __HIP_MEMORY_SCOPE_AGENT);
  return u.s;
}
__device__ __forceinline__ void hstore8(u16* p, u64 v) {
  __hip_atomic_store((u64*)p, v, __ATOMIC_RELAXED, __HIP_MEMORY_SCOPE_AGENT);
}
#define NBLK 256
// fence-free grid barrier: __syncthreads drains each thread's vmcnt (stores at IF),
// then one relaxed agent atomicAdd + spin. Counter monotonic within one kernel run.
__device__ __forceinline__ void gbar(unsigned* cnt, unsigned target) {
  __syncthreads();
  if (threadIdx.x == 0) {
    __hip_atomic_fetch_add(cnt, 1u, __ATOMIC_RELAXED, __HIP_MEMORY_SCOPE_AGENT);
    while (__hip_atomic_load(cnt, __ATOMIC_RELAXED, __HIP_MEMORY_SCOPE_AGENT) < target) {}
  }
  __syncthreads();
}

// ---------------- sizes ----------------
// B=64 T=50 L=64 VOCAB=30000 EMB=300 NF=256 HID=1024 OUT=32
#define NTILES 120         // (3+4+5)*10 conv K-step tiles of [4][256][8] bf16

// ---------------- prep: pack conv weights + Wp to bf16 + zero barrier ----------------
__global__ void prep_kernel(const float* __restrict__ cw3, const float* __restrict__ cw4,
                            const float* __restrict__ cw5, const float* __restrict__ h2ow,
                            u16* __restrict__ Wc, u16* __restrict__ Wpb,
                            unsigned* __restrict__ bar) {
  if (blockIdx.x == 0 && threadIdx.x == 0) *bar = 0u;   // re-zeroed every launch (ws is poisoned)
  const int NT = 1015808;  // 983040 Wc + 32768 Wpb
  for (int i = blockIdx.x * blockDim.x + threadIdx.x; i < NT; i += gridDim.x * blockDim.x) {
    if (i < 983040) {
      int T = i >> 13, q = i & 8191;
      int kg = q >> 11, n = (q >> 3) & 255, ke = q & 7;
      int bank, tb; const float* cw;
      if (T < 30) { bank = 0; tb = T; cw = cw3; }
      else if (T < 70) { bank = 1; tb = T - 30; cw = cw4; }
      else { bank = 2; tb = T - 70; cw = cw5; }
      int j = tb / 10, kc = tb - 10 * (tb / 10);
      int e = kc * 32 + kg * 8 + ke, fs = 3 + bank;
      float vv = (e < 300) ? cw[(n * 300 + e) * fs + j] : 0.f;
      Wc[i] = f2bf(vv);
    } else {
      int k = i - 983040; int c = k >> 10, kk = k & 1023;
      Wpb[k] = f2bf(h2ow[c * 1792 + 768 + kk]);
    }
  }
}

// ---------------- conv: fused embed-gather + 3-bank conv GEMM + relu-maxpool ----------------
// (unchanged: 560us, ~718 TF, MfmaUtil 32%)
__global__ __launch_bounds__(512, 1) void conv_kernel(
    const int* __restrict__ dlg, const float* __restrict__ emb, const u16* __restrict__ Wc,
    const float* __restrict__ cb3, const float* __restrict__ cb4, const float* __restrict__ cb5,
    float* __restrict__ feats) {
  extern __shared__ char smem[];
  u16* Al = (u16*)smem;                 // [128][328]
  u16* Bl = (u16*)(smem + 83968);       // [2][4][256][8]
  const int tid = threadIdx.x;
  const int u0 = blockIdx.x * 2;

  gload_lds16(Wc + tid * 8, Bl + tid * 8);
  gload_lds16(Wc + 4096 + tid * 8, Bl + 4096 + tid * 8);

  union Pack { u16 h[8]; int4 v; };
  #pragma unroll
  for (int p = 0; p < 10; ++p) {
    int task = tid + p * 512;           // 128 rows * 40 chunks
    int r = task / 40, ch = task - r * 40;
    int u = u0 + (r >> 6), tt = r & 63;
    int tok = dlg[u * 64 + tt];
    Pack pk;
    if (ch < 37) {
      const float4* s = (const float4*)(emb + tok * 300 + ch * 8);
      float4 x = s[0], y = s[1];
      pk.h[0] = f2bf(x.x); pk.h[1] = f2bf(x.y); pk.h[2] = f2bf(x.z); pk.h[3] = f2bf(x.w);
      pk.h[4] = f2bf(y.x); pk.h[5] = f2bf(y.y); pk.h[6] = f2bf(y.z); pk.h[7] = f2bf(y.w);
    } else if (ch == 37) {
      const float* s = emb + tok * 300;
      #pragma unroll
      for (int q = 0; q < 8; ++q) { int e = 296 + q; pk.h[q] = (e < 300) ? f2bf(s[e]) : (u16)0; }
    } else {
      pk.v = make_int4(0, 0, 0, 0);
    }
    *(int4*)&Al[r * 328 + ch * 8] = pk.v;
  }
  __syncthreads();

  const int l = tid & 63, v = tid >> 6;
  const int wm = v >> 2, wn = v & 3;
  const int lr = l & 15, lg = l >> 4;
  int T = 0, bb = 0;

  for (int bank = 0; bank < 3; ++bank) {
    const int fs = 3 + bank, Lout = 62 - bank;
    f32x4 acc[4][4];
    #pragma unroll
    for (int mi = 0; mi < 4; ++mi)
      #pragma unroll
      for (int ni = 0; ni < 4; ++ni) acc[mi][ni] = (f32x4){0.f, 0.f, 0.f, 0.f};

    for (int j = 0; j < fs; ++j) {
      for (int kc = 0; kc < 10; ++kc) {
        if (T + 1 < NTILES) {
          const u16* src = Wc + (T + 1) * 8192;
          u16* dst = Bl + (bb ^ 1) * 8192;
          gload_lds16(src + tid * 8, dst + tid * 8);
          gload_lds16(src + 4096 + tid * 8, dst + 4096 + tid * 8);
        }
        const int abase = (wm * 64 + lr + j) * 328 + kc * 32 + lg * 8;
        short8 af[4]; short8 bf[4];
        #pragma unroll
        for (int mi = 0; mi < 4; ++mi) af[mi] = *(const short8*)&Al[abase + mi * 16 * 328];
        const int bbase = bb * 8192 + lg * 2048 + (wn * 64 + lr) * 8;
        #pragma unroll
        for (int ni = 0; ni < 4; ++ni) bf[ni] = *(const short8*)&Bl[bbase + ni * 128];
        #pragma unroll
        for (int mi = 0; mi < 4; ++mi)
          #pragma unroll
          for (int ni = 0; ni < 4; ++ni) acc[mi][ni] = mfma16(af[mi], bf[ni], acc[mi][ni]);
        __syncthreads();
        bb ^= 1; ++T;
      }
    }
    const float* cb = (bank == 0) ? cb3 : ((bank == 1) ? cb4 : cb5);
    #pragma unroll
    for (int ni = 0; ni < 4; ++ni) {
      int f = wn * 64 + ni * 16 + lr;
      float bias = cb[f];
      float mx = 0.f;
      #pragma unroll
      for (int mi = 0; mi < 4; ++mi)
        #pragma unroll
        for (int r = 0; r < 4; ++r) {
          int t = mi * 16 + lg * 4 + r;
          float val = acc[mi][ni][r] + bias;
          if (t < Lout) mx = fmaxf(mx, val);
        }
      mx = fmaxf(mx, __shfl_xor(mx, 16, 64));
      mx = fmaxf(mx, __shfl_xor(mx, 32, 64));
      if (lg == 0) feats[(u0 + wm) * 768 + bank * 256 + f] = mx;
    }
  }
}

// ---------------- head_ft: headb[t][b][c] = h2o_b[c] + feats[b*50+t] . h2o_w[c][0:768] ----------------
__global__ __launch_bounds__(256) void headft_kernel(const float* __restrict__ feats,
                                                     const float* __restrict__ h2ow,
                                                     const float* __restrict__ h2ob,
                                                     float* __restrict__ headb) {
  extern __shared__ float Wt[];  // [768][33]
  const int tid = threadIdx.x, t = blockIdx.x;
  for (int i = tid; i < 32 * 768; i += 256) {
    int c = i / 768, k = i - 768 * c;
    Wt[k * 33 + c] = h2ow[c * 1792 + k];
  }
  __syncthreads();
  const int c = tid & 31, b0r = tid >> 5;
  float acc[8];
  #pragma unroll
  for (int i = 0; i < 8; ++i) acc[i] = h2ob[c];
  for (int k4 = 0; k4 < 192; ++k4) {
    float w0 = Wt[(k4 * 4 + 0) * 33 + c], w1 = Wt[(k4 * 4 + 1) * 33 + c];
    float w2 = Wt[(k4 * 4 + 2) * 33 + c], w3 = Wt[(k4 * 4 + 3) * 33 + c];
    #pragma unroll
    for (int i = 0; i < 8; ++i) {
      int b = b0r + 8 * i;
      float4 fv = *(const float4*)&feats[(b * 50 + t) * 768 + k4 * 4];
      acc[i] += fv.x * w0 + fv.y * w1 + fv.z * w2 + fv.w * w3;
    }
  }
  #pragma unroll
  for (int i = 0; i < 8; ++i) headb[t * 2048 + (b0r + 8 * i) * 32 + c] = acc[i];
}

// ---------------- persistent LSTM, hand-rolled fence-free barrier ----------------
// grid 256 x 256 threads (4 waves), 1 block/CU (LDS-bound) -> all co-resident.
// Block bk owns hidden units [4bk,4bk+4) of BOTH layers (16 gate rows each).
// Weights in LDS (XOR-swizzled); c0/c1 in LDS; h exchanged via IF-coherent atomics.
// whh1 term computed in phase A (h1p already loaded for pred); g1 partial carried in regs.
#define LDS_W0   0        // u16 [16][1024] whh0 slice (swizzled)
#define LDS_W1I  32768    // u16 [16][1024] wih1 slice (swizzled)
#define LDS_W1H  65536    // u16 [16][1024] whh1 slice (swizzled)
#define LDS_WI0  98304    // u16 [16][32]   wih0 slice
#define LDS_PRED 99328    // u16 [64][40]   pred(t-1) bf16 (pad 40: 2-way banks)
#define LDS_GST  104448   // f32 [64][17]   gate staging (pad 17)
#define LDS_HS   108800   // u16 [64][4]    h slice packing
#define LDS_C0   109312   // f32 [4][64]    c0 state
#define LDS_C1   110336   // f32 [4][64]    c1 state
#define LDS_B0   111360   // f32 [16]
#define LDS_B1   111424   // f32 [16]
#define LDS_TOT  111488

__device__ __forceinline__ short8 wread(const char* base, int lr, int kbyte) {
  return *(const short8*)(base + lr * 2048 + (kbyte ^ ((lr & 7) << 4)));
}

__global__ __launch_bounds__(256, 1) void lstm_pers(
    const float* __restrict__ whh0, const float* __restrict__ wih0,
    const float* __restrict__ whh1, const float* __restrict__ wih1,
    const float* __restrict__ b0, const float* __restrict__ b1,
    const u16* __restrict__ Wpb, const float* __restrict__ headb,
    u16* __restrict__ h0g, u16* __restrict__ h1g, float* __restrict__ dout,
    unsigned* __restrict__ bar) {
  extern __shared__ char smem[];
  u16* predl = (u16*)(smem + LDS_PRED);
  float* gst = (float*)(smem + LDS_GST);
  u16* hs = (u16*)(smem + LDS_HS);
  float* c0s = (float*)(smem + LDS_C0);
  float* c1s = (float*)(smem + LDS_C1);
  float* b0s = (float*)(smem + LDS_B0);
  float* b1s = (float*)(smem + LDS_B1);
  const int tid = threadIdx.x, bk = blockIdx.x;

  // ---- stage weight slices fp32 -> bf16 -> swizzled LDS (once) ----
  union Pack { u16 h[8]; int4 v; };
  for (int i = tid; i < 2048; i += 256) {           // 16 rows x 128 chunks of 8
    int n = i >> 7, ck = i & 127;
    int grow = (n >> 2) * 1024 + 4 * bk + (n & 3);
    int gof = grow * 1024 + ck * 8;
    int dst = n * 2048 + ((ck * 16) ^ ((n & 7) << 4));
    Pack p; float4 x, y; const float4* s;
    s = (const float4*)(whh0 + gof); x = s[0]; y = s[1];
    p.h[0]=f2bf(x.x); p.h[1]=f2bf(x.y); p.h[2]=f2bf(x.z); p.h[3]=f2bf(x.w);
    p.h[4]=f2bf(y.x); p.h[5]=f2bf(y.y); p.h[6]=f2bf(y.z); p.h[7]=f2bf(y.w);
    *(int4*)(smem + LDS_W0 + dst) = p.v;
    s = (const float4*)(wih1 + gof); x = s[0]; y = s[1];
    p.h[0]=f2bf(x.x); p.h[1]=f2bf(x.y); p.h[2]=f2bf(x.z); p.h[3]=f2bf(x.w);
    p.h[4]=f2bf(y.x); p.h[5]=f2bf(y.y); p.h[6]=f2bf(y.z); p.h[7]=f2bf(y.w);
    *(int4*)(smem + LDS_W1I + dst) = p.v;
    s = (const float4*)(whh1 + gof); x = s[0]; y = s[1];
    p.h[0]=f2bf(x.x); p.h[1]=f2bf(x.y); p.h[2]=f2bf(x.z); p.h[3]=f2bf(x.w);
    p.h[4]=f2bf(y.x); p.h[5]=f2bf(y.y); p.h[6]=f2bf(y.z); p.h[7]=f2bf(y.w);
    *(int4*)(smem + LDS_W1H + dst) = p.v;
  }
  if (tid < 64) {                                    // wih0 slice 16x32 (no swizzle)
    int n = tid >> 2, ck = tid & 3;
    int grow = (n >> 2) * 1024 + 4 * bk + (n & 3);
    const float4* s = (const float4*)(wih0 + grow * 32 + ck * 8);
    float4 x = s[0], y = s[1];
    Pack p;
    p.h[0]=f2bf(x.x); p.h[1]=f2bf(x.y); p.h[2]=f2bf(x.z); p.h[3]=f2bf(x.w);
    p.h[4]=f2bf(y.x); p.h[5]=f2bf(y.y); p.h[6]=f2bf(y.z); p.h[7]=f2bf(y.w);
    *(int4*)(smem + LDS_WI0 + n * 64 + ck * 16) = p.v;
  }
  if (tid < 16) {
    int grow = (tid >> 2) * 1024 + 4 * bk + (tid & 3);
    b0s[tid] = b0[grow]; b1s[tid] = b1[grow];
  }
  c0s[tid] = 0.f; c1s[tid] = 0.f;
  __syncthreads();

  const int l = tid & 63, wv = tid >> 6;
  const int lr = l & 15, lg = l >> 4;
  unsigned scount = 0;

  for (int t = 0; t < 50; ++t) {
    const int cur = t & 1, prv = cur ^ 1;
    const u16* h0p = h0g + prv * 65536;
    const u16* h1p = h1g + prv * 65536;

    // ---- phase A: pred(t-1)+whh1-partial (shared h1p loop) + layer-0 gates/state ----
    float bq1 = b1s[lr];
    f32x4 g1p = {bq1, bq1, bq1, bq1};
    float bq0 = b0s[lr];
    f32x4 g0 = {bq0, bq0, bq0, bq0};
    if (t > 0) {
      f32x4 z0 = {0.f,0.f,0.f,0.f}, z1 = {0.f,0.f,0.f,0.f};
      const u16* Ar = h1p + (wv * 16 + lr) * 1024 + lg * 8;
      const u16* Bp0 = Wpb + lr * 1024 + lg * 8;
      const u16* Bp1 = Wpb + (16 + lr) * 1024 + lg * 8;
      #pragma unroll 4
      for (int k = 0; k < 1024; k += 32) {
        short8 a = hload(Ar + k);
        z0 = mfma16(a, *(const short8*)(Bp0 + k), z0);
        z1 = mfma16(a, *(const short8*)(Bp1 + k), z1);
        g1p = mfma16(a, wread(smem + LDS_W1H, lr, k * 2 + lg * 16), g1p);
      }
      const float* hb = headb + (t - 1) * 2048;
      #pragma unroll
      for (int r = 0; r < 4; ++r) {
        int b = wv * 16 + lg * 4 + r;
        float p0 = sigm(z0[r] + hb[b * 32 + lr]);
        float p1 = sigm(z1[r] + hb[b * 32 + 16 + lr]);
        predl[b * 40 + lr] = f2bf(p0);
        predl[b * 40 + 16 + lr] = f2bf(p1);
        if (bk == 0) {
          dout[b * 1600 + (t - 1) * 32 + lr] = p0;
          dout[b * 1600 + (t - 1) * 32 + 16 + lr] = p1;
        }
      }
      // x-term (predl rows are wave-local) + whh0 term
      short8 ap = *(const short8*)&predl[(wv * 16 + lr) * 40 + lg * 8];
      short8 bi = *(const short8*)(smem + LDS_WI0 + lr * 64 + lg * 16);
      g0 = mfma16(ap, bi, g0);
      const u16* Ah = h0p + (wv * 16 + lr) * 1024 + lg * 8;
      #pragma unroll 4
      for (int k = 0; k < 1024; k += 32) {
        short8 a = hload(Ah + k);
        g0 = mfma16(a, wread(smem + LDS_W0, lr, k * 2 + lg * 16), g0);
      }
    }
    #pragma unroll
    for (int r = 0; r < 4; ++r) gst[(wv * 16 + lg * 4 + r) * 17 + lr] = g0[r];
    __syncthreads();
    {
      int b = tid & 63, hu = tid >> 6;
      float gi = gst[b * 17 + hu],     gf = gst[b * 17 + 4 + hu];
      float gg = gst[b * 17 + 8 + hu], go = gst[b * 17 + 12 + hu];
      float cold = c0s[hu * 64 + b];
      float c2 = sigm(gf) * cold + sigm(gi) * tanh_(gg);
      float h2 = sigm(go) * tanh_(c2);
      c0s[hu * 64 + b] = c2;
      hs[b * 4 + hu] = f2bf(h2);
    }
    __syncthreads();
    if (tid < 64) hstore8(h0g + cur * 65536 + tid * 1024 + 4 * bk, *(const u64*)&hs[tid * 4]);
    gbar(bar, (++scount) * NBLK);

    // ---- phase B: layer-1 gates/state (g1 = g1p + h0c @ wih1) ----
    const u16* h0c = h0g + cur * 65536;
    {
      const u16* Ah = h0c + (wv * 16 + lr) * 1024 + lg * 8;
      #pragma unroll 4
      for (int k = 0; k < 1024; k += 32) {
        short8 a = hload(Ah + k);
        g1p = mfma16(a, wread(smem + LDS_W1I, lr, k * 2 + lg * 16), g1p);
      }
    }
    #pragma unroll
    for (int r = 0; r < 4; ++r) gst[(wv * 16 + lg * 4 + r) * 17 + lr] = g1p[r];
    __syncthreads();
    {
      int b = tid & 63, hu = tid >> 6;
      float gi = gst[b * 17 + hu],     gf = gst[b * 17 + 4 + hu];
      float gg = gst[b * 17 + 8 + hu], go = gst[b * 17 + 12 + hu];
      float cold = c1s[hu * 64 + b];
      float c2 = sigm(gf) * cold + sigm(gi) * tanh_(gg);
      float h2 = sigm(go) * tanh_(c2);
      c1s[hu * 64 + b] = c2;
      hs[b * 4 + hu] = f2bf(h2);
    }
    __syncthreads();
    if (tid < 64) hstore8(h1g + cur * 65536 + tid * 1024 + 4 * bk, *(const u64*)&hs[tid * 4]);
    gbar(bar, (++scount) * NBLK);
  }

  // ---- final pred (t=49, cur=1) ----
  if (bk == 0) {
    f32x4 z0 = {0.f,0.f,0.f,0.f}, z1 = {0.f,0.f,0.f,0.f};
    const u16* Ar = h1g + 65536 + (wv * 16 + lr) * 1024 + lg * 8;
    const u16* Bp0 = Wpb + lr * 1024 + lg * 8;
    const u16* Bp1 = Wpb + (16 + lr) * 1024 + lg * 8;
    #pragma unroll 4
    for (int k = 0; k < 1024; k += 32) {
      short8 a = hload(Ar + k);
      z0 = mfma16(a, *(const short8*)(Bp0 + k), z0);
      z1 = mfma16(a, *(const short8*)(Bp1 + k), z1);
    }
    const float* hb = headb + 49 * 2048;
    #pragma unroll
    for (int r = 0; r < 4; ++r) {
      int b = wv * 16 + lg * 4 + r;
      dout[b * 1600 + 49 * 32 + lr] = sigm(z0[r] + hb[b * 32 + lr]);
      dout[b * 1600 + 49 * 32 + 16 + lr] = sigm(z1[r] + hb[b * 32 + 16 + lr]);
    }
  }
}

extern "C" void kernel_launch(void* const* d_in, const int* in_sizes, int n_in,
                              void* d_out, int out_size, void* d_ws, size_t ws_size,
                              hipStream_t stream) {
  const int* dlg = (const int*)d_in[0];
  const float* emb = (const float*)d_in[1];
  const float* cw3 = (const float*)d_in[2];
  const float* cb3 = (const float*)d_in[3];
  const float* cw4 = (const float*)d_in[4];
  const float* cb4 = (const float*)d_in[5];
  const float* cw5 = (const float*)d_in[6];
  const float* cb5 = (const float*)d_in[7];
  const float* wih0 = (const float*)d_in[8];
  const float* whh0 = (const float*)d_in[9];
  const float* b0 = (const float*)d_in[10];
  const float* wih1 = (const float*)d_in[11];
  const float* whh1 = (const float*)d_in[12];
  const float* b1 = (const float*)d_in[13];
  const float* h2ow = (const float*)d_in[14];
  const float* h2ob = (const float*)d_in[15];
  float* dout = (float*)d_out;
  char* ws = (char*)d_ws;

  u16* Wc    = (u16*)(ws + 0);             // 1966080 B
  u16* Wpb   = (u16*)(ws + 1966080);       // 65536 B
  float* feats = (float*)(ws + 2031616);   // 9830400 B
  float* headb = (float*)(ws + 11862016);  // 409600 B
  u16* h0g   = (u16*)(ws + 12271616);      // [2][64*1024] bf16
  u16* h1g   = (u16*)(ws + 12533760);      // [2][64*1024] bf16
  unsigned* bar = (unsigned*)(ws + 12795904);

  hipFuncSetAttribute((const void*)conv_kernel, hipFuncAttributeMaxDynamicSharedMemorySize, 116736);
  hipFuncSetAttribute((const void*)headft_kernel, hipFuncAttributeMaxDynamicSharedMemorySize, 101376);
  hipFuncSetAttribute((const void*)lstm_pers, hipFuncAttributeMaxDynamicSharedMemorySize, LDS_TOT);

  prep_kernel<<<dim3(1024), dim3(256), 0, stream>>>(cw3, cw4, cw5, h2ow, Wc, Wpb, bar);
  conv_kernel<<<dim3(1600), dim3(512), 116736, stream>>>(dlg, emb, Wc, cb3, cb4, cb5, feats);
  headft_kernel<<<dim3(50), dim3(256), 101376, stream>>>(feats, h2ow, h2ob, headb);
  lstm_pers<<<dim3(NBLK), dim3(256), LDS_TOT, stream>>>(whh0, wih0, whh1, wih1, b0, b1,
                                                        Wpb, headb, h0g, h1g, dout, bar);
}

// Round 6
// 2074.646 us; speedup vs baseline: 4.0862x; 1.2995x over previous
//
#include <hip/hip_runtime.h>

typedef unsigned short u16;
typedef unsigned long long u64;
typedef __attribute__((ext_vector_type(8))) short short8;
typedef __attribute__((ext_vector_type(4))) float f32x4;

__device__ __forceinline__ u16 f2bf(float f) {
  union { float f; unsigned u; } v; v.f = f;
  unsigned r = (v.u + 0x7fffu + ((v.u >> 16) & 1u)) >> 16;
  return (u16)r;
}
__device__ __forceinline__ float sigm(float x) { return 1.f / (1.f + __expf(-x)); }
__device__ __forceinline__ float tanh_(float x) { return 1.f - 2.f / (__expf(2.f * x) + 1.f); }
__device__ __forceinline__ f32x4 mfma16(short8 a, short8 b, f32x4 c) {
  return __builtin_amdgcn_mfma_f32_16x16x32_bf16(a, b, c, 0, 0, 0);
}
__device__ __forceinline__ void gload_lds16(const u16* g, u16* l) {
  __builtin_amdgcn_global_load_lds((const __attribute__((address_space(1))) void*)g,
                                   (__attribute__((address_space(3))) void*)l, 16, 0, 0);
}
// h exchange: producer uses 8B agent-scope atomic stores (write-through to IF);
// consumer uses inline-asm global_load_dwordx4 sc0 sc1 (L1+L2 bypass, IF-served,
// TA-coalesced, pipelined via counted vmcnt). No cache fences needed anywhere.
__device__ __forceinline__ void hstore8(u16* p, u64 v) {
  __hip_atomic_store((u64*)p, v, __ATOMIC_RELAXED, __HIP_MEMORY_SCOPE_AGENT);
}
#define GLDA(dst, b, OFF) asm volatile("global_load_dwordx4 %0, %1, off offset:" OFF " sc0 sc1" : "=v"(dst) : "v"(b) : "memory")
#define GLDC(dst, b, OFF) asm volatile("global_load_dwordx4 %0, %1, off offset:" OFF : "=v"(dst) : "v"(b) : "memory")
// counted wait + full sched fence (rule #18: MFMA hoists past asm waitcnt without it)
#define VMWAIT(N) do { asm volatile("s_waitcnt vmcnt(" #N ")" ::: "memory"); __builtin_amdgcn_sched_barrier(0); } while (0)

#define NBLK 256
// fence-free grid barrier (validated round 5): syncthreads drains vmcnt (stores at IF),
// then one relaxed agent atomicAdd + spin on monotonic counter.
__device__ __forceinline__ void gbar(unsigned* cnt, unsigned target) {
  __syncthreads();
  if (threadIdx.x == 0) {
    __hip_atomic_fetch_add(cnt, 1u, __ATOMIC_RELAXED, __HIP_MEMORY_SCOPE_AGENT);
    while (__hip_atomic_load(cnt, __ATOMIC_RELAXED, __HIP_MEMORY_SCOPE_AGENT) < target) {}
  }
  __syncthreads();
}

// ---------------- sizes ----------------
// B=64 T=50 L=64 VOCAB=30000 EMB=300 NF=256 HID=1024 OUT=32
#define NTILES 120

// ---------------- prep ----------------
__global__ void prep_kernel(const float* __restrict__ cw3, const float* __restrict__ cw4,
                            const float* __restrict__ cw5, const float* __restrict__ h2ow,
                            u16* __restrict__ Wc, u16* __restrict__ Wpb,
                            unsigned* __restrict__ bar) {
  if (blockIdx.x == 0 && threadIdx.x == 0) *bar = 0u;
  const int NT = 1015808;
  for (int i = blockIdx.x * blockDim.x + threadIdx.x; i < NT; i += gridDim.x * blockDim.x) {
    if (i < 983040) {
      int T = i >> 13, q = i & 8191;
      int kg = q >> 11, n = (q >> 3) & 255, ke = q & 7;
      int bank, tb; const float* cw;
      if (T < 30) { bank = 0; tb = T; cw = cw3; }
      else if (T < 70) { bank = 1; tb = T - 30; cw = cw4; }
      else { bank = 2; tb = T - 70; cw = cw5; }
      int j = tb / 10, kc = tb - 10 * (tb / 10);
      int e = kc * 32 + kg * 8 + ke, fs = 3 + bank;
      float vv = (e < 300) ? cw[(n * 300 + e) * fs + j] : 0.f;
      Wc[i] = f2bf(vv);
    } else {
      int k = i - 983040; int c = k >> 10, kk = k & 1023;
      Wpb[k] = f2bf(h2ow[c * 1792 + 768 + kk]);
    }
  }
}

// ---------------- conv (unchanged: 560us, ~718 TF) ----------------
__global__ __launch_bounds__(512, 1) void conv_kernel(
    const int* __restrict__ dlg, const float* __restrict__ emb, const u16* __restrict__ Wc,
    const float* __restrict__ cb3, const float* __restrict__ cb4, const float* __restrict__ cb5,
    float* __restrict__ feats) {
  extern __shared__ char smem[];
  u16* Al = (u16*)smem;
  u16* Bl = (u16*)(smem + 83968);
  const int tid = threadIdx.x;
  const int u0 = blockIdx.x * 2;

  gload_lds16(Wc + tid * 8, Bl + tid * 8);
  gload_lds16(Wc + 4096 + tid * 8, Bl + 4096 + tid * 8);

  union Pack { u16 h[8]; int4 v; };
  #pragma unroll
  for (int p = 0; p < 10; ++p) {
    int task = tid + p * 512;
    int r = task / 40, ch = task - r * 40;
    int u = u0 + (r >> 6), tt = r & 63;
    int tok = dlg[u * 64 + tt];
    Pack pk;
    if (ch < 37) {
      const float4* s = (const float4*)(emb + tok * 300 + ch * 8);
      float4 x = s[0], y = s[1];
      pk.h[0] = f2bf(x.x); pk.h[1] = f2bf(x.y); pk.h[2] = f2bf(x.z); pk.h[3] = f2bf(x.w);
      pk.h[4] = f2bf(y.x); pk.h[5] = f2bf(y.y); pk.h[6] = f2bf(y.z); pk.h[7] = f2bf(y.w);
    } else if (ch == 37) {
      const float* s = emb + tok * 300;
      #pragma unroll
      for (int q = 0; q < 8; ++q) { int e = 296 + q; pk.h[q] = (e < 300) ? f2bf(s[e]) : (u16)0; }
    } else {
      pk.v = make_int4(0, 0, 0, 0);
    }
    *(int4*)&Al[r * 328 + ch * 8] = pk.v;
  }
  __syncthreads();

  const int l = tid & 63, v = tid >> 6;
  const int wm = v >> 2, wn = v & 3;
  const int lr = l & 15, lg = l >> 4;
  int T = 0, bb = 0;

  for (int bank = 0; bank < 3; ++bank) {
    const int fs = 3 + bank, Lout = 62 - bank;
    f32x4 acc[4][4];
    #pragma unroll
    for (int mi = 0; mi < 4; ++mi)
      #pragma unroll
      for (int ni = 0; ni < 4; ++ni) acc[mi][ni] = (f32x4){0.f, 0.f, 0.f, 0.f};

    for (int j = 0; j < fs; ++j) {
      for (int kc = 0; kc < 10; ++kc) {
        if (T + 1 < NTILES) {
          const u16* src = Wc + (T + 1) * 8192;
          u16* dst = Bl + (bb ^ 1) * 8192;
          gload_lds16(src + tid * 8, dst + tid * 8);
          gload_lds16(src + 4096 + tid * 8, dst + 4096 + tid * 8);
        }
        const int abase = (wm * 64 + lr + j) * 328 + kc * 32 + lg * 8;
        short8 af[4]; short8 bf[4];
        #pragma unroll
        for (int mi = 0; mi < 4; ++mi) af[mi] = *(const short8*)&Al[abase + mi * 16 * 328];
        const int bbase = bb * 8192 + lg * 2048 + (wn * 64 + lr) * 8;
        #pragma unroll
        for (int ni = 0; ni < 4; ++ni) bf[ni] = *(const short8*)&Bl[bbase + ni * 128];
        #pragma unroll
        for (int mi = 0; mi < 4; ++mi)
          #pragma unroll
          for (int ni = 0; ni < 4; ++ni) acc[mi][ni] = mfma16(af[mi], bf[ni], acc[mi][ni]);
        __syncthreads();
        bb ^= 1; ++T;
      }
    }
    const float* cb = (bank == 0) ? cb3 : ((bank == 1) ? cb4 : cb5);
    #pragma unroll
    for (int ni = 0; ni < 4; ++ni) {
      int f = wn * 64 + ni * 16 + lr;
      float bias = cb[f];
      float mx = 0.f;
      #pragma unroll
      for (int mi = 0; mi < 4; ++mi)
        #pragma unroll
        for (int r = 0; r < 4; ++r) {
          int t = mi * 16 + lg * 4 + r;
          float val = acc[mi][ni][r] + bias;
          if (t < Lout) mx = fmaxf(mx, val);
        }
      mx = fmaxf(mx, __shfl_xor(mx, 16, 64));
      mx = fmaxf(mx, __shfl_xor(mx, 32, 64));
      if (lg == 0) feats[(u0 + wm) * 768 + bank * 256 + f] = mx;
    }
  }
}

// ---------------- head_ft (unchanged) ----------------
__global__ __launch_bounds__(256) void headft_kernel(const float* __restrict__ feats,
                                                     const float* __restrict__ h2ow,
                                                     const float* __restrict__ h2ob,
                                                     float* __restrict__ headb) {
  extern __shared__ float Wt[];
  const int tid = threadIdx.x, t = blockIdx.x;
  for (int i = tid; i < 32 * 768; i += 256) {
    int c = i / 768, k = i - 768 * c;
    Wt[k * 33 + c] = h2ow[c * 1792 + k];
  }
  __syncthreads();
  const int c = tid & 31, b0r = tid >> 5;
  float acc[8];
  #pragma unroll
  for (int i = 0; i < 8; ++i) acc[i] = h2ob[c];
  for (int k4 = 0; k4 < 192; ++k4) {
    float w0 = Wt[(k4 * 4 + 0) * 33 + c], w1 = Wt[(k4 * 4 + 1) * 33 + c];
    float w2 = Wt[(k4 * 4 + 2) * 33 + c], w3 = Wt[(k4 * 4 + 3) * 33 + c];
    #pragma unroll
    for (int i = 0; i < 8; ++i) {
      int b = b0r + 8 * i;
      float4 fv = *(const float4*)&feats[(b * 50 + t) * 768 + k4 * 4];
      acc[i] += fv.x * w0 + fv.y * w1 + fv.z * w2 + fv.w * w3;
    }
  }
  #pragma unroll
  for (int i = 0; i < 8; ++i) headb[t * 2048 + (b0r + 8 * i) * 32 + c] = acc[i];
}

// ---------------- persistent LSTM ----------------
#define LDS_W0   0
#define LDS_W1I  32768
#define LDS_W1H  65536
#define LDS_WI0  98304
#define LDS_PRED 99328
#define LDS_GST  104448
#define LDS_HS   108800
#define LDS_C0   109312
#define LDS_C1   110336
#define LDS_B0   111360
#define LDS_B1   111424
#define LDS_TOT  111488

__device__ __forceinline__ short8 wread(const char* base, int lr, int kbyte) {
  return *(const short8*)(base + lr * 2048 + (kbyte ^ ((lr & 7) << 4)));
}

// T1: 3-stream traversal (A sc-bypass + 2 cached B) in counted groups of 4 iters, depth 2
#define ISS1(s, g) do { u64 o = (u64)(g) * 256; \
  GLDA(tA[s][0], bA + o, "0");   GLDA(tA[s][1], bA + o, "64"); \
  GLDA(tA[s][2], bA + o, "128"); GLDA(tA[s][3], bA + o, "192"); \
  GLDC(tB0[s][0], bB0 + o, "0");   GLDC(tB0[s][1], bB0 + o, "64"); \
  GLDC(tB0[s][2], bB0 + o, "128"); GLDC(tB0[s][3], bB0 + o, "192"); \
  GLDC(tB1[s][0], bB1 + o, "0");   GLDC(tB1[s][1], bB1 + o, "64"); \
  GLDC(tB1[s][2], bB1 + o, "128"); GLDC(tB1[s][3], bB1 + o, "192"); } while (0)

// T2: 1-stream traversal (A sc-bypass, B from swizzled LDS) in groups of 8 iters, depth 2
#define ISS2(s, g) do { u64 o = (u64)(g) * 512; \
  GLDA(tA2[s][0], bA2 + o, "0");   GLDA(tA2[s][1], bA2 + o, "64"); \
  GLDA(tA2[s][2], bA2 + o, "128"); GLDA(tA2[s][3], bA2 + o, "192"); \
  GLDA(tA2[s][4], bA2 + o, "256"); GLDA(tA2[s][5], bA2 + o, "320"); \
  GLDA(tA2[s][6], bA2 + o, "384"); GLDA(tA2[s][7], bA2 + o, "448"); } while (0)

__global__ __launch_bounds__(256, 1) void lstm_pers(
    const float* __restrict__ whh0, const float* __restrict__ wih0,
    const float* __restrict__ whh1, const float* __restrict__ wih1,
    const float* __restrict__ b0, const float* __restrict__ b1,
    const u16* __restrict__ Wpb, const float* __restrict__ headb,
    u16* __restrict__ h0g, u16* __restrict__ h1g, float* __restrict__ dout,
    unsigned* __restrict__ bar) {
  extern __shared__ char smem[];
  u16* predl = (u16*)(smem + LDS_PRED);
  float* gst = (float*)(smem + LDS_GST);
  u16* hs = (u16*)(smem + LDS_HS);
  float* c0s = (float*)(smem + LDS_C0);
  float* c1s = (float*)(smem + LDS_C1);
  float* b0s = (float*)(smem + LDS_B0);
  float* b1s = (float*)(smem + LDS_B1);
  const int tid = threadIdx.x, bk = blockIdx.x;

  union Pack { u16 h[8]; int4 v; };
  for (int i = tid; i < 2048; i += 256) {
    int n = i >> 7, ck = i & 127;
    int grow = (n >> 2) * 1024 + 4 * bk + (n & 3);
    int gof = grow * 1024 + ck * 8;
    int dst = n * 2048 + ((ck * 16) ^ ((n & 7) << 4));
    Pack p; float4 x, y; const float4* s;
    s = (const float4*)(whh0 + gof); x = s[0]; y = s[1];
    p.h[0]=f2bf(x.x); p.h[1]=f2bf(x.y); p.h[2]=f2bf(x.z); p.h[3]=f2bf(x.w);
    p.h[4]=f2bf(y.x); p.h[5]=f2bf(y.y); p.h[6]=f2bf(y.z); p.h[7]=f2bf(y.w);
    *(int4*)(smem + LDS_W0 + dst) = p.v;
    s = (const float4*)(wih1 + gof); x = s[0]; y = s[1];
    p.h[0]=f2bf(x.x); p.h[1]=f2bf(x.y); p.h[2]=f2bf(x.z); p.h[3]=f2bf(x.w);
    p.h[4]=f2bf(y.x); p.h[5]=f2bf(y.y); p.h[6]=f2bf(y.z); p.h[7]=f2bf(y.w);
    *(int4*)(smem + LDS_W1I + dst) = p.v;
    s = (const float4*)(whh1 + gof); x = s[0]; y = s[1];
    p.h[0]=f2bf(x.x); p.h[1]=f2bf(x.y); p.h[2]=f2bf(x.z); p.h[3]=f2bf(x.w);
    p.h[4]=f2bf(y.x); p.h[5]=f2bf(y.y); p.h[6]=f2bf(y.z); p.h[7]=f2bf(y.w);
    *(int4*)(smem + LDS_W1H + dst) = p.v;
  }
  if (tid < 64) {
    int n = tid >> 2, ck = tid & 3;
    int grow = (n >> 2) * 1024 + 4 * bk + (n & 3);
    const float4* s = (const float4*)(wih0 + grow * 32 + ck * 8);
    float4 x = s[0], y = s[1];
    Pack p;
    p.h[0]=f2bf(x.x); p.h[1]=f2bf(x.y); p.h[2]=f2bf(x.z); p.h[3]=f2bf(x.w);
    p.h[4]=f2bf(y.x); p.h[5]=f2bf(y.y); p.h[6]=f2bf(y.z); p.h[7]=f2bf(y.w);
    *(int4*)(smem + LDS_WI0 + n * 64 + ck * 16) = p.v;
  }
  if (tid < 16) {
    int grow = (tid >> 2) * 1024 + 4 * bk + (tid & 3);
    b0s[tid] = b0[grow]; b1s[tid] = b1[grow];
  }
  c0s[tid] = 0.f; c1s[tid] = 0.f;
  __syncthreads();

  const int l = tid & 63, wv = tid >> 6;
  const int lr = l & 15, lg = l >> 4;
  unsigned scount = 0;

  for (int t = 0; t < 50; ++t) {
    const int cur = t & 1, prv = cur ^ 1;
    const u16* h0p = h0g + prv * 65536;
    const u16* h1p = h1g + prv * 65536;

    float bq1 = b1s[lr];
    f32x4 g1p = {bq1, bq1, bq1, bq1};
    float bq0 = b0s[lr];
    f32x4 g0 = {bq0, bq0, bq0, bq0};
    float p0s[4], p1s[4];

    if (t > 0) {
      // ---- T1: pred(t-1) z0,z1 + whh1-partial, one h1p traversal ----
      f32x4 z0 = {0.f,0.f,0.f,0.f}, z1 = {0.f,0.f,0.f,0.f};
      {
        const u64 bA  = (u64)(h1p + (wv * 16 + lr) * 1024 + lg * 8);
        const u64 bB0 = (u64)(Wpb + lr * 1024 + lg * 8);
        const u64 bB1 = bB0 + 32768;
        short8 tA[3][4], tB0[3][4], tB1[3][4];
        VMWAIT(0);
        ISS1(0, 0); ISS1(1, 1);
        #pragma unroll
        for (int g = 0; g < 8; ++g) {
          const int s = g % 3;
          if (g < 6) { const int s2 = (g + 2) % 3; ISS1(s2, g + 2); }
          if (g < 6)      { VMWAIT(24); }
          else if (g == 6){ VMWAIT(12); }
          else            { VMWAIT(0); }
          #pragma unroll
          for (int i = 0; i < 4; ++i) {
            const int it = g * 4 + i;
            z0  = mfma16(tA[s][i], tB0[s][i], z0);
            z1  = mfma16(tA[s][i], tB1[s][i], z1);
            g1p = mfma16(tA[s][i], wread(smem + LDS_W1H, lr, it * 64 + lg * 16), g1p);
          }
        }
      }
      const float* hb = headb + (t - 1) * 2048;
      #pragma unroll
      for (int r = 0; r < 4; ++r) {
        int b = wv * 16 + lg * 4 + r;
        float p0 = sigm(z0[r] + hb[b * 32 + lr]);
        float p1 = sigm(z1[r] + hb[b * 32 + 16 + lr]);
        p0s[r] = p0; p1s[r] = p1;
        predl[b * 40 + lr] = f2bf(p0);
        predl[b * 40 + 16 + lr] = f2bf(p1);
      }
      // x-term (wave-local predl rows)
      short8 ap = *(const short8*)&predl[(wv * 16 + lr) * 40 + lg * 8];
      short8 bi = *(const short8*)(smem + LDS_WI0 + lr * 64 + lg * 16);
      g0 = mfma16(ap, bi, g0);
      // ---- T2: whh0 term ----
      {
        const u64 bA2 = (u64)(h0p + (wv * 16 + lr) * 1024 + lg * 8);
        short8 tA2[3][8];
        VMWAIT(0);
        ISS2(0, 0); ISS2(1, 1);
        #pragma unroll
        for (int g = 0; g < 4; ++g) {
          const int s = g % 3;
          if (g < 2) { const int s2 = (g + 2) % 3; ISS2(s2, g + 2); }
          if (g < 2)      { VMWAIT(16); }
          else if (g == 2){ VMWAIT(8); }
          else            { VMWAIT(0); }
          #pragma unroll
          for (int i = 0; i < 8; ++i) {
            const int it = g * 8 + i;
            g0 = mfma16(tA2[s][i], wread(smem + LDS_W0, lr, it * 64 + lg * 16), g0);
          }
        }
      }
    }
    #pragma unroll
    for (int r = 0; r < 4; ++r) gst[(wv * 16 + lg * 4 + r) * 17 + lr] = g0[r];
    __syncthreads();
    {
      int b = tid & 63, hu = tid >> 6;
      float gi = gst[b * 17 + hu],     gf = gst[b * 17 + 4 + hu];
      float gg = gst[b * 17 + 8 + hu], go = gst[b * 17 + 12 + hu];
      float cold = c0s[hu * 64 + b];
      float c2 = sigm(gf) * cold + sigm(gi) * tanh_(gg);
      float h2 = sigm(go) * tanh_(c2);
      c0s[hu * 64 + b] = c2;
      hs[b * 4 + hu] = f2bf(h2);
    }
    __syncthreads();
    if (tid < 64) hstore8(h0g + cur * 65536 + tid * 1024 + 4 * bk, *(const u64*)&hs[tid * 4]);
    if (t > 0 && bk == 0) {
      #pragma unroll
      for (int r = 0; r < 4; ++r) {
        int b = wv * 16 + lg * 4 + r;
        dout[b * 1600 + (t - 1) * 32 + lr] = p0s[r];
        dout[b * 1600 + (t - 1) * 32 + 16 + lr] = p1s[r];
      }
    }
    gbar(bar, (++scount) * NBLK);

    // ---- phase B: g1 = g1p + h0c @ wih1 ----
    {
      const u64 bA2 = (u64)(h0g + cur * 65536 + (wv * 16 + lr) * 1024 + lg * 8);
      short8 tA2[3][8];
      VMWAIT(0);
      ISS2(0, 0); ISS2(1, 1);
      #pragma unroll
      for (int g = 0; g < 4; ++g) {
        const int s = g % 3;
        if (g < 2) { const int s2 = (g + 2) % 3; ISS2(s2, g + 2); }
        if (g < 2)      { VMWAIT(16); }
        else if (g == 2){ VMWAIT(8); }
        else            { VMWAIT(0); }
        #pragma unroll
        for (int i = 0; i < 8; ++i) {
          const int it = g * 8 + i;
          g1p = mfma16(tA2[s][i], wread(smem + LDS_W1I, lr, it * 64 + lg * 16), g1p);
        }
      }
    }
    #pragma unroll
    for (int r = 0; r < 4; ++r) gst[(wv * 16 + lg * 4 + r) * 17 + lr] = g1p[r];
    __syncthreads();
    {
      int b = tid & 63, hu = tid >> 6;
      float gi = gst[b * 17 + hu],     gf = gst[b * 17 + 4 + hu];
      float gg = gst[b * 17 + 8 + hu], go = gst[b * 17 + 12 + hu];
      float cold = c1s[hu * 64 + b];
      float c2 = sigm(gf) * cold + sigm(gi) * tanh_(gg);
      float h2 = sigm(go) * tanh_(c2);
      c1s[hu * 64 + b] = c2;
      hs[b * 4 + hu] = f2bf(h2);
    }
    __syncthreads();
    if (tid < 64) hstore8(h1g + cur * 65536 + tid * 1024 + 4 * bk, *(const u64*)&hs[tid * 4]);
    gbar(bar, (++scount) * NBLK);
  }

  // ---- final pred (t=49, cur=1) ----
  if (bk == 0) {
    f32x4 z0 = {0.f,0.f,0.f,0.f}, z1 = {0.f,0.f,0.f,0.f};
    {
      const u64 bA  = (u64)(h1g + 65536 + (wv * 16 + lr) * 1024 + lg * 8);
      const u64 bB0 = (u64)(Wpb + lr * 1024 + lg * 8);
      const u64 bB1 = bB0 + 32768;
      short8 tA[3][4], tB0[3][4], tB1[3][4];
      VMWAIT(0);
      ISS1(0, 0); ISS1(1, 1);
      #pragma unroll
      for (int g = 0; g < 8; ++g) {
        const int s = g % 3;
        if (g < 6) { const int s2 = (g + 2) % 3; ISS1(s2, g + 2); }
        if (g < 6)      { VMWAIT(24); }
        else if (g == 6){ VMWAIT(12); }
        else            { VMWAIT(0); }
        #pragma unroll
        for (int i = 0; i < 4; ++i) {
          z0 = mfma16(tA[s][i], tB0[s][i], z0);
          z1 = mfma16(tA[s][i], tB1[s][i], z1);
        }
      }
    }
    const float* hb = headb + 49 * 2048;
    #pragma unroll
    for (int r = 0; r < 4; ++r) {
      int b = wv * 16 + lg * 4 + r;
      dout[b * 1600 + 49 * 32 + lr] = sigm(z0[r] + hb[b * 32 + lr]);
      dout[b * 1600 + 49 * 32 + 16 + lr] = sigm(z1[r] + hb[b * 32 + 16 + lr]);
    }
  }
}

extern "C" void kernel_launch(void* const* d_in, const int* in_sizes, int n_in,
                              void* d_out, int out_size, void* d_ws, size_t ws_size,
                              hipStream_t stream) {
  const int* dlg = (const int*)d_in[0];
  const float* emb = (const float*)d_in[1];
  const float* cw3 = (const float*)d_in[2];
  const float* cb3 = (const float*)d_in[3];
  const float* cw4 = (const float*)d_in[4];
  const float* cb4 = (const float*)d_in[5];
  const float* cw5 = (const float*)d_in[6];
  const float* cb5 = (const float*)d_in[7];
  const float* wih0 = (const float*)d_in[8];
  const float* whh0 = (const float*)d_in[9];
  const float* b0 = (const float*)d_in[10];
  const float* wih1 = (const float*)d_in[11];
  const float* whh1 = (const float*)d_in[12];
  const float* b1 = (const float*)d_in[13];
  const float* h2ow = (const float*)d_in[14];
  const float* h2ob = (const float*)d_in[15];
  float* dout = (float*)d_out;
  char* ws = (char*)d_ws;

  u16* Wc    = (u16*)(ws + 0);
  u16* Wpb   = (u16*)(ws + 1966080);
  float* feats = (float*)(ws + 2031616);
  float* headb = (float*)(ws + 11862016);
  u16* h0g   = (u16*)(ws + 12271616);
  u16* h1g   = (u16*)(ws + 12533760);
  unsigned* bar = (unsigned*)(ws + 12795904);

  hipFuncSetAttribute((const void*)conv_kernel, hipFuncAttributeMaxDynamicSharedMemorySize, 116736);
  hipFuncSetAttribute((const void*)headft_kernel, hipFuncAttributeMaxDynamicSharedMemorySize, 101376);
  hipFuncSetAttribute((const void*)lstm_pers, hipFuncAttributeMaxDynamicSharedMemorySize, LDS_TOT);

  prep_kernel<<<dim3(1024), dim3(256), 0, stream>>>(cw3, cw4, cw5, h2ow, Wc, Wpb, bar);
  conv_kernel<<<dim3(1600), dim3(512), 116736, stream>>>(dlg, emb, Wc, cb3, cb4, cb5, feats);
  headft_kernel<<<dim3(50), dim3(256), 101376, stream>>>(feats, h2ow, h2ob, headb);
  lstm_pers<<<dim3(NBLK), dim3(256), LDS_TOT, stream>>>(whh0, wih0, whh1, wih1, b0, b1,
                                                        Wpb, headb, h0g, h1g, dout, bar);
}